// Round 2
// baseline (248.873 us; speedup 1.0000x reference)
//
#include <hip/hip_runtime.h>

#define NB  128
#define NT  8192
#define TPB 512
#define PT  16           // elements per thread (contiguous)
#define NW  (TPB / 64)   // waves per block

__global__ __launch_bounds__(TPB, 8) void mrpcen_kernel(
    const float* __restrict__ x,
    const float* __restrict__ log_alpha,
    const float* __restrict__ log_delta,
    const float* __restrict__ log_r,
    float* __restrict__ out)
{
    __shared__ float4 wtot[NW];   // per-wave scan totals (128 B)

    const int tid  = threadIdx.x;
    const int lane = tid & 63;
    const int wv   = tid >> 6;
    const int bf   = blockIdx.x;          // 0..1023
    const int b    = bf >> 7;
    const int f    = bf & (NB - 1);

    const float* xrow = x + (size_t)bf * NT;

    // per-band params (stored in log space; f is block-uniform -> scalar loads)
    const float alpha  = __expf(log_alpha[f]);
    const float r      = __expf(log_r[f]);
    const float delta  = __expf(log_delta[f]);
    const float deltar = __expf(r * log_delta[f]);   // delta^r

    // smoothing coefficients s_t = (sqrt(1+4t^2)-1)/(2t^2); A16 = (1-s)^16
    float s[4], A16[4];
    const float tv[4] = {2.f, 8.f, 32.f, 128.f};
#pragma unroll
    for (int t = 0; t < 4; t++) {
        float t2 = tv[t] * tv[t];
        s[t] = (sqrtf(1.f + 4.f * t2) - 1.f) / (2.f * t2);
        float a = 1.f - s[t];
        a = a * a; a = a * a; a = a * a; a = a * a;   // (1-s)^16
        A16[t] = a;
    }

    // ---- load own 16 contiguous elements straight from global ----
    float xc[PT];
    const float4* xv = reinterpret_cast<const float4*>(xrow + tid * PT);
#pragma unroll
    for (int j = 0; j < 4; j++) {
        float4 v = xv[j];
        xc[4 * j + 0] = v.x; xc[4 * j + 1] = v.y;
        xc[4 * j + 2] = v.z; xc[4 * j + 3] = v.w;
    }
    const float m0 = xrow[0];   // scan init m[-1] = x[0] (block-uniform)

    // ---- local affine compose (B with m_in = 0) for 4 rates ----
    float B[4] = {0.f, 0.f, 0.f, 0.f};
#pragma unroll
    for (int i = 0; i < PT; i++) {
        float xi = xc[i];
#pragma unroll
        for (int t = 0; t < 4; t++)
            B[t] = s[t] * xi + (1.f - s[t]) * B[t];
    }

    // ---- wave-level inclusive scan (Hillis-Steele with factor squaring) ----
    float S[4] = {B[0], B[1], B[2], B[3]};
    float F[4] = {A16[0], A16[1], A16[2], A16[3]};
#pragma unroll
    for (int d = 1; d < 64; d <<= 1) {
#pragma unroll
        for (int t = 0; t < 4; t++) {
            float up = __shfl_up(S[t], d, 64);
            up = (lane >= d) ? up : 0.f;
            S[t] += F[t] * up;
            F[t] *= F[t];
        }
    }

    if (lane == 63) wtot[wv] = make_float4(S[0], S[1], S[2], S[3]);
    __syncthreads();

    // A1024 = A16^64
    float A1024[4];
#pragma unroll
    for (int t = 0; t < 4; t++) {
        float a = A16[t];
        a = a * a; a = a * a; a = a * a; a = a * a; a = a * a; a = a * a;
        A1024[t] = a;
    }

    // wave-incoming state: m_wave = A1024^wv * m0 + P (P = combined B of earlier waves)
    float P[4]  = {0.f, 0.f, 0.f, 0.f};
    float Ap[4] = {1.f, 1.f, 1.f, 1.f};
    for (int w = 0; w < wv; w++) {
        float4 W = wtot[w];
        P[0] = W.x + A1024[0] * P[0];
        P[1] = W.y + A1024[1] * P[1];
        P[2] = W.z + A1024[2] * P[2];
        P[3] = W.w + A1024[3] * P[3];
#pragma unroll
        for (int t = 0; t < 4; t++) Ap[t] *= A1024[t];
    }

    // thread-incoming state: m_in = A16^lane * m_wave + S_{lane-1}
    float mtin[4];
#pragma unroll
    for (int t = 0; t < 4; t++) {
        float sp = __shfl_up(S[t], 1, 64);
        sp = lane ? sp : 0.f;
        float p = 1.f, base = A16[t];
        int e = lane;
#pragma unroll
        for (int bit = 0; bit < 6; bit++) {
            if (e & 1) p *= base;
            base *= base;
            e >>= 1;
        }
        float mwave = Ap[t] * m0 + P[t];
        mtin[t] = p * mwave + sp;
    }

    // ---- epilogue: recurrence + PCEN, direct stores from registers ----
#pragma unroll
    for (int t = 0; t < 4; t++) {
        const float st = s[t], a1 = 1.f - s[t];
        float m = mtin[t];
        float* op = out + (((size_t)b * 4 + t) * NB + f) * (size_t)NT + tid * PT;
#pragma unroll
        for (int j = 0; j < 4; j++) {
            float ov[4];
#pragma unroll
            for (int q = 0; q < 4; q++) {
                float xi = xc[4 * j + q];
                m = st * xi + a1 * m;
                float smooth = __expf(-alpha * __logf(1e-5f + m));   // (eps+m)^(-alpha)
                ov[q] = __expf(r * __logf(xi * smooth + delta)) - deltar;
            }
            reinterpret_cast<float4*>(op)[j] = make_float4(ov[0], ov[1], ov[2], ov[3]);
        }
    }
}

extern "C" void kernel_launch(void* const* d_in, const int* in_sizes, int n_in,
                              void* d_out, int out_size, void* d_ws, size_t ws_size,
                              hipStream_t stream) {
    const float* x         = (const float*)d_in[0];
    const float* log_alpha = (const float*)d_in[1];
    const float* log_delta = (const float*)d_in[2];
    const float* log_r     = (const float*)d_in[3];
    float* out = (float*)d_out;

    // one block per (b, f) row: 8 * 128 = 1024 blocks x 512 threads
    mrpcen_kernel<<<dim3(8 * NB), dim3(TPB), 0, stream>>>(
        x, log_alpha, log_delta, log_r, out);
}

// Round 4
// 216.712 us; speedup vs baseline: 1.1484x; 1.1484x over previous
//
#include <hip/hip_runtime.h>

#define NB  128
#define NT  8192
#define TPB 512
#define NPH 4            // phases: each thread owns one float4 per phase, stride 2048
#define NW  (TPB / 64)   // 8 waves per block

typedef float floatx4 __attribute__((ext_vector_type(4)));   // clang vector, OK for nontemporal builtins

__global__ __launch_bounds__(TPB, 8) void mrpcen_kernel(
    const float* __restrict__ x,
    const float* __restrict__ log_alpha,
    const float* __restrict__ log_delta,
    const float* __restrict__ log_r,
    float* __restrict__ out)
{
    __shared__ float4 wtot[NPH][NW];   // per-(phase,wave) scan totals, 512 B

    const int tid  = threadIdx.x;
    const int lane = tid & 63;
    const int wv   = tid >> 6;
    const int bf   = blockIdx.x;          // 0..1023
    const int b    = bf >> 7;
    const int f    = bf & (NB - 1);

    const float* xrow = x + (size_t)bf * NT;

    // per-band params (runtime, block-uniform -> scalarized)
    const float alpha  = __expf(log_alpha[f]);
    const float r      = __expf(log_r[f]);
    const float delta  = __expf(log_delta[f]);
    const float deltar = __expf(r * log_delta[f]);   // delta^r

    // smoothing coeffs depend only on T_VALUES = {2,8,32,128}: compile-time.
    // s = (sqrt(1+4t^2)-1)/(2t^2)
    const float s[4] = {0.39038820320220757f, 0.11743140267094843f,
                        0.030765533214461896f, 0.0077820420262371225f};
    float a1[4], A4[4], Aw[4];
#pragma unroll
    for (int t = 0; t < 4; t++) {
        a1[t] = 1.f - s[t];
        float a = a1[t] * a1[t]; a = a * a;          // (1-s)^4
        A4[t] = a;
        float w = a;                                  // (1-s)^256 = A4^64
#pragma unroll
        for (int k = 0; k < 6; k++) w = w * w;
        Aw[t] = w;
    }

    // ---- coalesced loads: one float4 per phase (1 KB contiguous per wave-instr) ----
    float xc[NPH * 4];
#pragma unroll
    for (int p = 0; p < NPH; p++) {
        float4 v = *reinterpret_cast<const float4*>(xrow + p * 2048 + tid * 4);
        xc[p * 4 + 0] = v.x; xc[p * 4 + 1] = v.y;
        xc[p * 4 + 2] = v.z; xc[p * 4 + 3] = v.w;
    }
    const float m0 = xrow[0];   // scan init m[-1] = x[0]

    // ---- local affine compose per phase (B with m_in = 0) ----
    float S[NPH][4];
#pragma unroll
    for (int p = 0; p < NPH; p++) {
#pragma unroll
        for (int t = 0; t < 4; t++) {
            float bacc = 0.f;
#pragma unroll
            for (int i = 0; i < 4; i++) bacc = s[t] * xc[p * 4 + i] + a1[t] * bacc;
            S[p][t] = bacc;
        }
    }

    // ---- wave-level inclusive scans (factor-squaring Hillis-Steele, no LDS) ----
#pragma unroll
    for (int p = 0; p < NPH; p++) {
        float F[4] = {A4[0], A4[1], A4[2], A4[3]};
#pragma unroll
        for (int d = 1; d < 64; d <<= 1) {
#pragma unroll
            for (int t = 0; t < 4; t++) {
                float up = __shfl_up(S[p][t], d, 64);
                if (lane >= d) S[p][t] += F[t] * up;
                F[t] *= F[t];
            }
        }
    }

    if (lane == 63) {
#pragma unroll
        for (int p = 0; p < NPH; p++)
            wtot[p][wv] = make_float4(S[p][0], S[p][1], S[p][2], S[p][3]);
    }
    __syncthreads();   // the only block barrier

    // within-wave exclusive value (state after lane-1 chunks, from m=0)
#pragma unroll
    for (int p = 0; p < NPH; p++) {
#pragma unroll
        for (int t = 0; t < 4; t++) {
            float sp = __shfl_up(S[p][t], 1, 64);
            S[p][t] = lane ? sp : 0.f;
        }
    }

    // pw = A4^lane (binary powering)
    float pw[4];
#pragma unroll
    for (int t = 0; t < 4; t++) {
        float pwr = 1.f, base = A4[t];
        int e = lane;
#pragma unroll
        for (int bit = 0; bit < 6; bit++) {
            if (e & 1) pwr *= base;
            base *= base; e >>= 1;
        }
        pw[t] = pwr;
    }

    // serial combine over the 32 (phase, wave) chunks in time order;
    // fold thread-incoming state directly into S
    float AccA[4] = {1.f, 1.f, 1.f, 1.f};
    float AccB[4] = {0.f, 0.f, 0.f, 0.f};
#pragma unroll
    for (int p = 0; p < NPH; p++) {
#pragma unroll
        for (int w = 0; w < NW; w++) {
            if (w == wv) {   // wave-uniform branch
#pragma unroll
                for (int t = 0; t < 4; t++) {
                    float mwin = AccA[t] * m0 + AccB[t];   // wave-incoming state
                    S[p][t] = pw[t] * mwin + S[p][t];      // thread-incoming state
                }
            }
            float4 W = wtot[p][w];
            AccB[0] = W.x + Aw[0] * AccB[0]; AccA[0] *= Aw[0];
            AccB[1] = W.y + Aw[1] * AccB[1]; AccA[1] *= Aw[1];
            AccB[2] = W.z + Aw[2] * AccB[2]; AccA[2] *= Aw[2];
            AccB[3] = W.w + Aw[3] * AccB[3]; AccA[3] *= Aw[3];
        }
    }

    // ---- epilogue: recurrence + PCEN, one coalesced nt-float4 store per (t,p) ----
#pragma unroll
    for (int t = 0; t < 4; t++) {
        const float st = s[t], a1t = a1[t];
        float* oplane = out + (((size_t)b * 4 + t) * NB + f) * (size_t)NT + tid * 4;
#pragma unroll
        for (int p = 0; p < NPH; p++) {
            float m = S[p][t];
            float ov[4];
#pragma unroll
            for (int i = 0; i < 4; i++) {
                float xi = xc[p * 4 + i];
                m = st * xi + a1t * m;
                float smooth = __expf(-alpha * __logf(1e-5f + m));   // (eps+m)^(-alpha)
                ov[i] = __expf(r * __logf(xi * smooth + delta)) - deltar;
            }
            floatx4 o = {ov[0], ov[1], ov[2], ov[3]};
            __builtin_nontemporal_store(o,
                reinterpret_cast<floatx4*>(oplane + p * 2048));
        }
    }
}

extern "C" void kernel_launch(void* const* d_in, const int* in_sizes, int n_in,
                              void* d_out, int out_size, void* d_ws, size_t ws_size,
                              hipStream_t stream) {
    const float* x         = (const float*)d_in[0];
    const float* log_alpha = (const float*)d_in[1];
    const float* log_delta = (const float*)d_in[2];
    const float* log_r     = (const float*)d_in[3];
    float* out = (float*)d_out;

    // one block per (b, f) row: 8 * 128 = 1024 blocks x 512 threads
    mrpcen_kernel<<<dim3(8 * NB), dim3(TPB), 0, stream>>>(
        x, log_alpha, log_delta, log_r, out);
}